// Round 17
// baseline (66.851 us; speedup 1.0000x reference)
//
#include <hip/hip_runtime.h>

#define T_SEQ 2048
#define DIMM 512
#define NH 8
#define HD 64
#define BB 2
#define CHUNK 64
#define NCHUNK 32
#define EPSV 1e-6f
#define LDST 72    // bf16 LDS row stride (shorts)
#define CST 132    // proj epilogue bounce-tile row stride (shorts)
#define PBUF 12288 // proj double-buffer stride in shorts (As 4096 + Bs 8192)

typedef __attribute__((ext_vector_type(8))) short bf16x8;
typedef __attribute__((ext_vector_type(4))) short s16x4;
typedef __attribute__((ext_vector_type(4))) float f32x4;

static __device__ inline short f2bf(float f) {
    union { float f; unsigned u; } v; v.f = f;
    unsigned r = v.u + 0x7FFFu + ((v.u >> 16) & 1u);
    return (short)(r >> 16);
}
static __device__ inline float bf2f(short s) {
    union { unsigned u; float f; } v; v.u = ((unsigned)(unsigned short)s) << 16;
    return v.f;
}
static __device__ __forceinline__ void gload_lds16(const void* g, void* l) {
    __builtin_amdgcn_global_load_lds(
        (__attribute__((address_space(1))) void*)g,
        (__attribute__((address_space(3))) void*)l, 16, 0, 0);
}

// ---------------------------------------------------------------------------
// Kernel 0: fp32 -> bf16. x -> xb; {Wq,Wk,Wv} -> Wcat[1536][512]; Wo -> Wob.
// grid 1536, block 256
// ---------------------------------------------------------------------------
__global__ __launch_bounds__(256) void convert_kernel(
    const float* __restrict__ x, const float* __restrict__ Wq,
    const float* __restrict__ Wk, const float* __restrict__ Wv,
    const float* __restrict__ Wo,
    short* __restrict__ xb, short* __restrict__ Wcat, short* __restrict__ Wob)
{
    const int u = blockIdx.x * 256 + threadIdx.x;
    const float* src; short* dst;
    if (u < 262144) {
        src = x + (size_t)u * 8; dst = xb + (size_t)u * 8;
    } else {
        const int v = u - 262144;
        const int o = (v & 32767) * 8;
        if (v < 32768)       { src = Wq + o; dst = Wcat + o; }
        else if (v < 65536)  { src = Wk + o; dst = Wcat + 262144 + o; }
        else if (v < 98304)  { src = Wv + o; dst = Wcat + 524288 + o; }
        else                 { src = Wo + o; dst = Wob + o; }
    }
    const float4 a = *(const float4*)src;
    const float4 b = *(const float4*)(src + 4);
    *(bf16x8*)dst = (bf16x8){f2bf(a.x), f2bf(a.y), f2bf(a.z), f2bf(a.w),
                             f2bf(b.x), f2bf(b.y), f2bf(b.z), f2bf(b.w)};
}

// ---------------------------------------------------------------------------
// Kernel 1: fused QKV projection GEMM (R12 config: 64x128 tile, 2-ahead
// counted-vmcnt pipeline, source-preswizzled LDS).
// grid (64, 12), block 256; 48 KB LDS
// ---------------------------------------------------------------------------
__global__ __launch_bounds__(256) void proj_mfma_kernel(
    const short* __restrict__ xb, const short* __restrict__ Wcat,
    short* __restrict__ Qs, short* __restrict__ Kbf,
    short* __restrict__ Ktb, short* __restrict__ Vt)
{
    __shared__ short S[2 * PBUF];
    short* Cs = S;
    const int m0 = blockIdx.x * 64;
    const int n0 = blockIdx.y * 128;
    const int which = blockIdx.y >> 2;
    const int tid = threadIdx.x;
    const int lane = tid & 63, w = tid >> 6;
    const int wr = w >> 1, wc = w & 1;
    const int fr = lane & 15, fg = lane >> 4;
    const int lrr = lane >> 3;
    const int sl8 = ((lane & 7) ^ lrr) * 8;
    const int xr = fr & 7;
    f32x4 acc[2][4] = {};

    #define STAGE(buf, k0)                                                       \
        {                                                                        \
            short* As_ = S + (buf) * PBUF;                                       \
            short* Bs_ = As_ + 4096;                                             \
            _Pragma("unroll")                                                    \
            for (int it = 0; it < 2; it++) {                                     \
                const int r0 = w * 16 + it * 8;                                  \
                gload_lds16(xb + (size_t)(m0 + r0 + lrr) * DIMM + (k0) + sl8,    \
                            &As_[r0 * 64]);                                      \
            }                                                                    \
            _Pragma("unroll")                                                    \
            for (int it = 0; it < 4; it++) {                                     \
                const int r0 = w * 32 + it * 8;                                  \
                gload_lds16(Wcat + (size_t)(n0 + r0 + lrr) * DIMM + (k0) + sl8,  \
                            &Bs_[r0 * 64]);                                      \
            }                                                                    \
        }

    STAGE(0, 0);
    STAGE(1, 64);

    #pragma unroll
    for (int t = 0; t < 8; t++) {
        if (t < 7) asm volatile("s_waitcnt vmcnt(6)" ::: "memory");
        else       asm volatile("s_waitcnt vmcnt(0)" ::: "memory");
        __builtin_amdgcn_sched_barrier(0);
        __builtin_amdgcn_s_barrier();
        __builtin_amdgcn_sched_barrier(0);
        {
            const short* As = S + (t & 1) * PBUF;
            const short* Bs = As + 4096;
            #pragma unroll
            for (int ks = 0; ks < 2; ks++) {
                const int cc = (((ks << 2) + fg) ^ xr) * 8;
                bf16x8 af[2], bfr[4];
                #pragma unroll
                for (int i = 0; i < 2; i++)
                    af[i] = *(const bf16x8*)&As[(wr * 32 + i * 16 + fr) * 64 + cc];
                #pragma unroll
                for (int j = 0; j < 4; j++)
                    bfr[j] = *(const bf16x8*)&Bs[(wc * 64 + j * 16 + fr) * 64 + cc];
                #pragma unroll
                for (int i = 0; i < 2; i++)
                    #pragma unroll
                    for (int j = 0; j < 4; j++)
                        acc[i][j] = __builtin_amdgcn_mfma_f32_16x16x32_bf16(af[i], bfr[j], acc[i][j], 0, 0, 0);
            }
        }
        __builtin_amdgcn_sched_barrier(0);
        __builtin_amdgcn_s_barrier();
        __builtin_amdgcn_sched_barrier(0);
        if (t < 6) STAGE(t & 1, (t + 2) * 64);
    }
    #undef STAGE

    #pragma unroll
    for (int i = 0; i < 2; i++)
        #pragma unroll
        for (int j = 0; j < 4; j++)
            #pragma unroll
            for (int reg = 0; reg < 4; reg++) {
                float val = acc[i][j][reg];
                if (which == 1) val = (val > 0.f) ? (val + 1.f) : __expf(val);
                Cs[(wr * 32 + i * 16 + fg * 4 + reg) * CST + wc * 64 + j * 16 + fr] = f2bf(val);
            }
    __syncthreads();

    const int b = m0 >> 11, t0 = m0 & (T_SEQ - 1);
    if (which == 0) {
        if (tid < 128) {
            const int r = tid & 63, hh = tid >> 6;
            const int head = (blockIdx.y & 3) * 2 + hh;
            s16x4 seg[16];
            #pragma unroll
            for (int s = 0; s < 16; s++) seg[s] = *(const s16x4*)&Cs[r * CST + hh * 64 + s * 4];
            float mx = -1e30f;
            #pragma unroll
            for (int s = 0; s < 16; s++)
                #pragma unroll
                for (int k = 0; k < 4; k++) mx = fmaxf(mx, bf2f(seg[s][k]));
            float sum = 0.f;
            #pragma unroll
            for (int s = 0; s < 16; s++)
                #pragma unroll
                for (int k = 0; k < 4; k++) sum += __expf(bf2f(seg[s][k]) - mx);
            const float inv = 1.f / sum;
            short* qp = Qs + (((size_t)(b * NH + head)) * T_SEQ + t0 + r) * HD;
            #pragma unroll
            for (int s = 0; s < 16; s += 2) {
                bf16x8 o;
                #pragma unroll
                for (int k = 0; k < 4; k++) o[k] = f2bf(__expf(bf2f(seg[s][k]) - mx) * inv);
                #pragma unroll
                for (int k = 0; k < 4; k++) o[4 + k] = f2bf(__expf(bf2f(seg[s + 1][k]) - mx) * inv);
                *(bf16x8*)(qp + s * 4) = o;
            }
        }
    } else if (which == 1) {
        if (tid < 128) {
            const int r = tid & 63, hh = tid >> 6;
            const int head = (blockIdx.y & 3) * 2 + hh;
            short* kp = Kbf + (((size_t)(b * NH + head)) * T_SEQ + t0 + r) * HD;
            #pragma unroll
            for (int s = 0; s < 8; s++) {
                const s16x4 a = *(const s16x4*)&Cs[r * CST + hh * 64 + s * 8];
                const s16x4 bq = *(const s16x4*)&Cs[r * CST + hh * 64 + s * 8 + 4];
                *(bf16x8*)(kp + s * 8) = (bf16x8){a[0], a[1], a[2], a[3], bq[0], bq[1], bq[2], bq[3]};
            }
        }
        {
            const int c = tid & 127, half = tid >> 7;
            const int head = (blockIdx.y & 3) * 2 + (c >> 6);
            const int d = c & 63;
            short* ktp = Ktb + (((size_t)(b * NH + head)) * HD + d) * T_SEQ + t0 + half * 32;
            #pragma unroll
            for (int s = 0; s < 4; s++) {
                bf16x8 o;
                #pragma unroll
                for (int k = 0; k < 8; k++) o[k] = Cs[(half * 32 + s * 8 + k) * CST + c];
                *(bf16x8*)(ktp + s * 8) = o;
            }
        }
    } else {
        const int c = tid & 127, half = tid >> 7;
        const int head = (blockIdx.y & 3) * 2 + (c >> 6);
        const int e = c & 63;
        short* vtp = Vt + (((size_t)(b * NH + head)) * HD + e) * T_SEQ + t0 + half * 32;
        #pragma unroll
        for (int s = 0; s < 4; s++) {
            bf16x8 o;
            #pragma unroll
            for (int k = 0; k < 8; k++) o[k] = Cs[(half * 32 + s * 8 + k) * CST + c];
            *(bf16x8*)(vtp + s * 8) = o;
        }
    }
}

// ---------------------------------------------------------------------------
// Kernel 2: per-chunk sums via MFMA: S[e][d] = sum_t Vt[e][t]*Kt[d][t]; ksum[d].
// (raw per-chunk sums; prefix is folded into intra)
// grid 512, block 256
// ---------------------------------------------------------------------------
__global__ __launch_bounds__(256) void chunk_sum_kernel(
    const short* __restrict__ Ktb, const short* __restrict__ Vt,
    float* __restrict__ Schunk, float* __restrict__ kchunk)
{
    __shared__ short VtL[64 * LDST];
    __shared__ short KtL[64 * LDST];
    __shared__ float ksp[4][64];
    const int bh = blockIdx.x >> 5, c = blockIdx.x & 31;
    const int tid = threadIdx.x;
    const int lane = tid & 63, w = tid >> 6;
    const int fr = lane & 15, fg = lane >> 4;
    #pragma unroll
    for (int it = 0; it < 2; it++) {
        const int qi = it * 256 + tid;
        const int r = qi >> 3, c8 = (qi & 7) * 8;
        *(bf16x8*)&VtL[r * LDST + c8] =
            *(const bf16x8*)(Vt + ((size_t)(bh * HD) + r) * T_SEQ + c * CHUNK + c8);
        *(bf16x8*)&KtL[r * LDST + c8] =
            *(const bf16x8*)(Ktb + ((size_t)(bh * HD) + r) * T_SEQ + c * CHUNK + c8);
    }
    __syncthreads();
    f32x4 acc[4] = {};
    #pragma unroll
    for (int ks = 0; ks < 2; ks++) {
        const bf16x8 av = *(const bf16x8*)&VtL[(w * 16 + fr) * LDST + ks * 32 + fg * 8];
        #pragma unroll
        for (int j = 0; j < 4; j++) {
            const bf16x8 bk = *(const bf16x8*)&KtL[(j * 16 + fr) * LDST + ks * 32 + fg * 8];
            acc[j] = __builtin_amdgcn_mfma_f32_16x16x32_bf16(av, bk, acc[j], 0, 0, 0);
        }
    }
    float* Sout = Schunk + ((size_t)bh * NCHUNK + c) * 4096;
    #pragma unroll
    for (int j = 0; j < 4; j++)
        #pragma unroll
        for (int reg = 0; reg < 4; reg++)
            Sout[(w * 16 + fg * 4 + reg) * 64 + j * 16 + fr] = acc[j][reg];
    float ps = 0.f;
    #pragma unroll
    for (int t = 0; t < 16; t++) ps += bf2f(KtL[lane * LDST + w * 16 + t]);
    ksp[w][lane] = ps;
    __syncthreads();
    if (tid < 64)
        kchunk[((size_t)bh * NCHUNK + c) * 64 + tid] =
            ksp[0][tid] + ksp[1][tid] + ksp[2][tid] + ksp[3][tid];
}

// ---------------------------------------------------------------------------
// Kernel 3: intra-chunk via MFMA, with in-block exclusive prefix over raw
// chunk sums (replaces the scan kernel).
// qn = Qs/(Ksum+eps); A = tril(qn.K^T); attn = qn.Sp^T + A.V^T  (bf16 out)
// grid 512, block 256
// ---------------------------------------------------------------------------
__global__ __launch_bounds__(256) void intra_kernel(
    const short* __restrict__ Qs, const short* __restrict__ Kbf,
    const short* __restrict__ Vt, const float* __restrict__ Schunk,
    const float* __restrict__ kchunk, short* __restrict__ attnb)
{
    __shared__ short B1[64 * LDST];
    __shared__ short B2[64 * LDST];
    __shared__ short KL[64 * LDST];
    __shared__ short VtL[64 * LDST];
    __shared__ short QnL[64 * LDST];
    __shared__ float gsum[4][64];
    __shared__ float kpre[64];
    const int bh = blockIdx.x >> 5, c = blockIdx.x & 31;
    const int tid = threadIdx.x;
    const int lane = tid & 63, w = tid >> 6;
    const int fr = lane & 15, fg = lane >> 4;
    const size_t tdbase = ((size_t)bh * T_SEQ + c * CHUNK) * HD;
    #pragma unroll
    for (int it = 0; it < 2; it++) {
        const int qi = it * 256 + tid;
        const int r = qi >> 3, c8 = (qi & 7) * 8;
        *(bf16x8*)&B1[r * LDST + c8]  = *(const bf16x8*)(Qs + tdbase + r * HD + c8);
        *(bf16x8*)&KL[r * LDST + c8]  = *(const bf16x8*)(Kbf + tdbase + r * HD + c8);
        *(bf16x8*)&VtL[r * LDST + c8] =
            *(const bf16x8*)(Vt + ((size_t)(bh * HD) + r) * T_SEQ + c * CHUNK + c8);
    }
    // Sp = sum of raw chunk-sums 0..c-1 (exclusive prefix), computed in-block.
    // Thread owns 16 contiguous elements: coalesced f32 streaming from L2.
    {
        const float* Sbase = Schunk + ((size_t)bh * NCHUNK) * 4096 + tid * 16;
        float accf[16] = {};
        for (int cc = 0; cc < c; ++cc) {
            #pragma unroll
            for (int e = 0; e < 16; e += 4) {
                const float4 v = *(const float4*)(Sbase + (size_t)cc * 4096 + e);
                accf[e]     += v.x; accf[e + 1] += v.y;
                accf[e + 2] += v.z; accf[e + 3] += v.w;
            }
        }
        const int r = (tid * 16) >> 6, col0 = (tid * 16) & 63;
        #pragma unroll
        for (int e = 0; e < 16; e += 4)
            *(s16x4*)&B2[r * LDST + col0 + e] =
                (s16x4){f2bf(accf[e]), f2bf(accf[e + 1]), f2bf(accf[e + 2]), f2bf(accf[e + 3])};
    }
    if (tid < 64) {
        float s = 0.f;
        const float* kb = kchunk + (size_t)bh * NCHUNK * 64 + tid;
        for (int cc = 0; cc < c; ++cc) s += kb[cc * 64];
        kpre[tid] = s;
    }
    __syncthreads();
    {
        float s = 0.f;
        #pragma unroll
        for (int t = 0; t < 16; t++) s += bf2f(KL[(w * 16 + t) * LDST + lane]);
        gsum[w][lane] = s;
    }
    __syncthreads();
    {
        float run = kpre[lane];
        for (int gg = 0; gg < w; gg++) run += gsum[gg][lane];
        #pragma unroll
        for (int t0 = 0; t0 < 16; t0++) {
            const int t = w * 16 + t0;
            run += bf2f(KL[t * LDST + lane]);
            const float qv = bf2f(B1[t * LDST + lane]);
            QnL[t * LDST + lane] = f2bf(qv / (run + EPSV));
        }
    }
    __syncthreads();
    {
        f32x4 a1[4] = {};
        #pragma unroll
        for (int ks = 0; ks < 2; ks++) {
            const bf16x8 aq = *(const bf16x8*)&QnL[(w * 16 + fr) * LDST + ks * 32 + fg * 8];
            #pragma unroll
            for (int j = 0; j < 4; j++) {
                const bf16x8 bk = *(const bf16x8*)&KL[(j * 16 + fr) * LDST + ks * 32 + fg * 8];
                a1[j] = __builtin_amdgcn_mfma_f32_16x16x32_bf16(aq, bk, a1[j], 0, 0, 0);
            }
        }
        const int trow = w * 16 + fg * 4;
        #pragma unroll
        for (int j = 0; j < 4; j++)
            #pragma unroll
            for (int reg = 0; reg < 4; reg++) {
                const int t = trow + reg, s = j * 16 + fr;
                B1[t * LDST + s] = (s <= t) ? f2bf(a1[j][reg]) : (short)0;
            }
    }
    __syncthreads();
    {
        f32x4 a2[4] = {};
        #pragma unroll
        for (int ks = 0; ks < 2; ks++) {
            const bf16x8 aq = *(const bf16x8*)&QnL[(w * 16 + fr) * LDST + ks * 32 + fg * 8];
            const bf16x8 aa = *(const bf16x8*)&B1[(w * 16 + fr) * LDST + ks * 32 + fg * 8];
            #pragma unroll
            for (int j = 0; j < 4; j++) {
                const bf16x8 bs = *(const bf16x8*)&B2[(j * 16 + fr) * LDST + ks * 32 + fg * 8];
                const bf16x8 bv = *(const bf16x8*)&VtL[(j * 16 + fr) * LDST + ks * 32 + fg * 8];
                a2[j] = __builtin_amdgcn_mfma_f32_16x16x32_bf16(aq, bs, a2[j], 0, 0, 0);
                a2[j] = __builtin_amdgcn_mfma_f32_16x16x32_bf16(aa, bv, a2[j], 0, 0, 0);
            }
        }
        short* ap = attnb + tdbase;
        const int trow = w * 16 + fg * 4;
        #pragma unroll
        for (int j = 0; j < 4; j++)
            #pragma unroll
            for (int reg = 0; reg < 4; reg++)
                ap[(trow + reg) * HD + j * 16 + fr] = f2bf(a2[j][reg]);
    }
}

// ---------------------------------------------------------------------------
// Kernel 4: out = attn(permuted) @ Wo^T + bo, 64x64 tile. grid (64,8), 256
// ---------------------------------------------------------------------------
__global__ __launch_bounds__(256) void outproj_mfma_kernel(
    const short* __restrict__ attnb, const short* __restrict__ Wob,
    const float* __restrict__ bo, float* __restrict__ out)
{
    __shared__ short As[64 * 64];
    __shared__ short Bs[64 * 64];
    const int m0 = blockIdx.x * 64;
    const int n0 = blockIdx.y * 64;
    const int tid = threadIdx.x;
    const int lane = tid & 63, w = tid >> 6;
    const int fr = lane & 15, fg = lane >> 4;
    const int lr = lane >> 3, lc = (lane & 7) * 8;
    const int b = m0 >> 11, tbase = m0 & (T_SEQ - 1);
    f32x4 acc[4] = {};
    for (int k0 = 0; k0 < DIMM; k0 += 64) {
        const int h = k0 >> 6;
        #pragma unroll
        for (int it = 0; it < 2; it++) {
            const int r0 = w * 16 + it * 8;
            gload_lds16(attnb + (((size_t)(b * NH + h)) * T_SEQ + tbase + r0 + lr) * HD + lc,
                        &As[r0 * 64]);
            gload_lds16(Wob + (size_t)(n0 + r0 + lr) * DIMM + k0 + lc, &Bs[r0 * 64]);
        }
        __syncthreads();
        #pragma unroll
        for (int ks = 0; ks < 2; ks++) {
            const bf16x8 af = *(const bf16x8*)&As[(w * 16 + fr) * 64 + ks * 32 + fg * 8];
            #pragma unroll
            for (int j = 0; j < 4; j++) {
                const bf16x8 bfr = *(const bf16x8*)&Bs[(j * 16 + fr) * 64 + ks * 32 + fg * 8];
                acc[j] = __builtin_amdgcn_mfma_f32_16x16x32_bf16(af, bfr, acc[j], 0, 0, 0);
            }
        }
        __syncthreads();
    }
    #pragma unroll
    for (int j = 0; j < 4; j++)
        #pragma unroll
        for (int reg = 0; reg < 4; reg++) {
            const int m = m0 + w * 16 + fg * 4 + reg;
            const int n = n0 + j * 16 + fr;
            out[(size_t)m * DIMM + n] = acc[j][reg] + bo[n];
        }
}

// ---------------------------------------------------------------------------
extern "C" void kernel_launch(void* const* d_in, const int* in_sizes, int n_in,
                              void* d_out, int out_size, void* d_ws, size_t ws_size,
                              hipStream_t stream)
{
    const float* x  = (const float*)d_in[0];
    const float* Wq = (const float*)d_in[1];
    const float* Wk = (const float*)d_in[2];
    const float* Wv = (const float*)d_in[3];
    const float* Wo = (const float*)d_in[4];
    const float* bo = (const float*)d_in[5];
    float* out = (float*)d_out;

    const size_t NELEM = (size_t)BB * T_SEQ * DIMM;   // 2,097,152
    short* xb    = (short*)d_ws;                      // [4096][512]
    short* Wcat  = xb + NELEM;                        // [1536][512]
    short* Wob   = Wcat + 786432;                     // [512][512]
    short* Qs    = Wob + 262144;
    short* Kbf   = Qs + NELEM;
    short* Ktb   = Kbf + NELEM;
    short* Vt    = Ktb + NELEM;
    short* attnb = Vt + NELEM;
    float* Schunk = (float*)(attnb + NELEM);                    // [bh][c][e][d] raw sums
    float* kchunk = Schunk + (size_t)BB * NH * NCHUNK * 4096;   // [bh][c][d] raw sums

    convert_kernel<<<dim3(1536), 256, 0, stream>>>(x, Wq, Wk, Wv, Wo, xb, Wcat, Wob);
    proj_mfma_kernel<<<dim3(64, 12), 256, 0, stream>>>(xb, Wcat, Qs, Kbf, Ktb, Vt);
    chunk_sum_kernel<<<dim3(BB * NH * NCHUNK), 256, 0, stream>>>(Ktb, Vt, Schunk, kchunk);
    intra_kernel<<<dim3(BB * NH * NCHUNK), 256, 0, stream>>>(Qs, Kbf, Vt, Schunk, kchunk, attnb);
    outproj_mfma_kernel<<<dim3(64, 8), 256, 0, stream>>>(attnb, Wob, bo, out);
}

// Round 18
// 54.781 us; speedup vs baseline: 1.2203x; 1.2203x over previous
//
#include <hip/hip_runtime.h>

#define T_SEQ 2048
#define DIMM 512
#define NH 8
#define HD 64
#define BB 2
#define CHUNK 64
#define NCHUNK 32
#define EPSV 1e-6f
#define LDST 72    // bf16 LDS row stride (shorts)
#define CST 132    // proj epilogue bounce-tile row stride (shorts)
#define PBUF 12288 // proj double-buffer stride in shorts (As 4096 + Bs 8192)

typedef __attribute__((ext_vector_type(8))) short bf16x8;
typedef __attribute__((ext_vector_type(4))) short s16x4;
typedef __attribute__((ext_vector_type(4))) float f32x4;

static __device__ inline short f2bf(float f) {
    union { float f; unsigned u; } v; v.f = f;
    unsigned r = v.u + 0x7FFFu + ((v.u >> 16) & 1u);
    return (short)(r >> 16);
}
static __device__ inline float bf2f(short s) {
    union { unsigned u; float f; } v; v.u = ((unsigned)(unsigned short)s) << 16;
    return v.f;
}
static __device__ __forceinline__ void gload_lds16(const void* g, void* l) {
    __builtin_amdgcn_global_load_lds(
        (__attribute__((address_space(1))) void*)g,
        (__attribute__((address_space(3))) void*)l, 16, 0, 0);
}

// ---------------------------------------------------------------------------
// Kernel 0: fp32 -> bf16. x -> xb; {Wq,Wk,Wv} -> Wcat[1536][512]; Wo -> Wob.
// grid 1536, block 256
// ---------------------------------------------------------------------------
__global__ __launch_bounds__(256) void convert_kernel(
    const float* __restrict__ x, const float* __restrict__ Wq,
    const float* __restrict__ Wk, const float* __restrict__ Wv,
    const float* __restrict__ Wo,
    short* __restrict__ xb, short* __restrict__ Wcat, short* __restrict__ Wob)
{
    const int u = blockIdx.x * 256 + threadIdx.x;   // 8-float unit id
    const float* src; short* dst;
    if (u < 262144) {
        src = x + (size_t)u * 8; dst = xb + (size_t)u * 8;
    } else {
        const int v = u - 262144;
        const int o = (v & 32767) * 8;
        if (v < 32768)       { src = Wq + o; dst = Wcat + o; }
        else if (v < 65536)  { src = Wk + o; dst = Wcat + 262144 + o; }
        else if (v < 98304)  { src = Wv + o; dst = Wcat + 524288 + o; }
        else                 { src = Wo + o; dst = Wob + o; }
    }
    const float4 a = *(const float4*)src;
    const float4 b = *(const float4*)(src + 4);
    *(bf16x8*)dst = (bf16x8){f2bf(a.x), f2bf(a.y), f2bf(a.z), f2bf(a.w),
                             f2bf(b.x), f2bf(b.y), f2bf(b.z), f2bf(b.w)};
}

// ---------------------------------------------------------------------------
// Kernel 1: fused QKV projection GEMM, 64x128 tile, 2-ahead counted-vmcnt
// pipeline (T4): vmcnt(6) + raw s_barrier, no full drains in the K-loop.
// C[4096][1536] = xb @ Wcat^T:
//   cols 0-511  (Q): serial-row softmax -> Qs [b,h,t,d]
//   cols 512-1023 (K): elu+1 -> Kbf [b,h,t,d] and Ktb [b,h,d,t]
//   cols 1024-1535 (V): -> Vt [b,h,e,t]
// grid (64, 12), block 256 (4 waves, each 32x64 output); 48 KB LDS
// ---------------------------------------------------------------------------
__global__ __launch_bounds__(256) void proj_mfma_kernel(
    const short* __restrict__ xb, const short* __restrict__ Wcat,
    short* __restrict__ Qs, short* __restrict__ Kbf,
    short* __restrict__ Ktb, short* __restrict__ Vt)
{
    __shared__ short S[2 * PBUF];   // 48 KB: 2 x (As[64][64] | Bs[128][64])
    short* Cs = S;                  // epilogue bounce tile aliases buf0
    const int m0 = blockIdx.x * 64;
    const int n0 = blockIdx.y * 128;          // global row into stacked Wcat
    const int which = blockIdx.y >> 2;
    const int tid = threadIdx.x;
    const int lane = tid & 63, w = tid >> 6;
    const int wr = w >> 1, wc = w & 1;
    const int fr = lane & 15, fg = lane >> 4;
    const int lrr = lane >> 3;                 // row-within-8 for staging
    const int sl8 = ((lane & 7) ^ lrr) * 8;    // inverse-swizzled source k-chunk
    const int xr = fr & 7;                     // read-side swizzle key
    f32x4 acc[2][4] = {};

    // per-wave stage of tile k0 into buffer buf (6 gload_lds per wave)
    #define STAGE(buf, k0)                                                       \
        {                                                                        \
            short* As_ = S + (buf) * PBUF;                                       \
            short* Bs_ = As_ + 4096;                                             \
            _Pragma("unroll")                                                    \
            for (int it = 0; it < 2; it++) {                                     \
                const int r0 = w * 16 + it * 8;                                  \
                gload_lds16(xb + (size_t)(m0 + r0 + lrr) * DIMM + (k0) + sl8,    \
                            &As_[r0 * 64]);                                      \
            }                                                                    \
            _Pragma("unroll")                                                    \
            for (int it = 0; it < 4; it++) {                                     \
                const int r0 = w * 32 + it * 8;                                  \
                gload_lds16(Wcat + (size_t)(n0 + r0 + lrr) * DIMM + (k0) + sl8,  \
                            &Bs_[r0 * 64]);                                      \
            }                                                                    \
        }

    STAGE(0, 0);
    STAGE(1, 64);

    #pragma unroll
    for (int t = 0; t < 8; t++) {
        // wait for THIS wave's tile-t loads (6 newest may stay outstanding)
        if (t < 7) asm volatile("s_waitcnt vmcnt(6)" ::: "memory");
        else       asm volatile("s_waitcnt vmcnt(0)" ::: "memory");
        __builtin_amdgcn_sched_barrier(0);
        __builtin_amdgcn_s_barrier();      // all waves' tile-t loads visible
        __builtin_amdgcn_sched_barrier(0);
        {
            const short* As = S + (t & 1) * PBUF;
            const short* Bs = As + 4096;
            #pragma unroll
            for (int ks = 0; ks < 2; ks++) {
                const int cc = (((ks << 2) + fg) ^ xr) * 8;
                bf16x8 af[2], bfr[4];
                #pragma unroll
                for (int i = 0; i < 2; i++)
                    af[i] = *(const bf16x8*)&As[(wr * 32 + i * 16 + fr) * 64 + cc];
                #pragma unroll
                for (int j = 0; j < 4; j++)
                    bfr[j] = *(const bf16x8*)&Bs[(wc * 64 + j * 16 + fr) * 64 + cc];
                #pragma unroll
                for (int i = 0; i < 2; i++)
                    #pragma unroll
                    for (int j = 0; j < 4; j++)
                        acc[i][j] = __builtin_amdgcn_mfma_f32_16x16x32_bf16(af[i], bfr[j], acc[i][j], 0, 0, 0);
            }
        }
        __builtin_amdgcn_sched_barrier(0);
        __builtin_amdgcn_s_barrier();      // all waves done reading buf[t&1]
        __builtin_amdgcn_sched_barrier(0);
        if (t < 6) STAGE(t & 1, (t + 2) * 64);   // refill the freed buffer
    }
    #undef STAGE

    // bounce acc -> Cs (elu+1 fused for K); both buffers dead post-barrier
    #pragma unroll
    for (int i = 0; i < 2; i++)
        #pragma unroll
        for (int j = 0; j < 4; j++)
            #pragma unroll
            for (int reg = 0; reg < 4; reg++) {
                float val = acc[i][j][reg];
                if (which == 1) val = (val > 0.f) ? (val + 1.f) : __expf(val);
                Cs[(wr * 32 + i * 16 + fg * 4 + reg) * CST + wc * 64 + j * 16 + fr] = f2bf(val);
            }
    __syncthreads();

    const int b = m0 >> 11, t0 = m0 & (T_SEQ - 1);
    if (which == 0) {
        if (tid < 128) {
            const int r = tid & 63, hh = tid >> 6;
            const int head = (blockIdx.y & 3) * 2 + hh;
            s16x4 seg[16];
            #pragma unroll
            for (int s = 0; s < 16; s++) seg[s] = *(const s16x4*)&Cs[r * CST + hh * 64 + s * 4];
            float mx = -1e30f;
            #pragma unroll
            for (int s = 0; s < 16; s++)
                #pragma unroll
                for (int k = 0; k < 4; k++) mx = fmaxf(mx, bf2f(seg[s][k]));
            float sum = 0.f;
            #pragma unroll
            for (int s = 0; s < 16; s++)
                #pragma unroll
                for (int k = 0; k < 4; k++) sum += __expf(bf2f(seg[s][k]) - mx);
            const float inv = 1.f / sum;
            short* qp = Qs + (((size_t)(b * NH + head)) * T_SEQ + t0 + r) * HD;
            #pragma unroll
            for (int s = 0; s < 16; s += 2) {
                bf16x8 o;
                #pragma unroll
                for (int k = 0; k < 4; k++) o[k] = f2bf(__expf(bf2f(seg[s][k]) - mx) * inv);
                #pragma unroll
                for (int k = 0; k < 4; k++) o[4 + k] = f2bf(__expf(bf2f(seg[s + 1][k]) - mx) * inv);
                *(bf16x8*)(qp + s * 4) = o;
            }
        }
    } else if (which == 1) {
        // Kbf row copy (already elu'd)
        if (tid < 128) {
            const int r = tid & 63, hh = tid >> 6;
            const int head = (blockIdx.y & 3) * 2 + hh;
            short* kp = Kbf + (((size_t)(b * NH + head)) * T_SEQ + t0 + r) * HD;
            #pragma unroll
            for (int s = 0; s < 8; s++) {
                const s16x4 a = *(const s16x4*)&Cs[r * CST + hh * 64 + s * 8];
                const s16x4 bq = *(const s16x4*)&Cs[r * CST + hh * 64 + s * 8 + 4];
                *(bf16x8*)(kp + s * 8) = (bf16x8){a[0], a[1], a[2], a[3], bq[0], bq[1], bq[2], bq[3]};
            }
        }
        // Ktb transpose: thread (c, half) -> 32 rows of column c
        {
            const int c = tid & 127, half = tid >> 7;
            const int head = (blockIdx.y & 3) * 2 + (c >> 6);
            const int d = c & 63;
            short* ktp = Ktb + (((size_t)(b * NH + head)) * HD + d) * T_SEQ + t0 + half * 32;
            #pragma unroll
            for (int s = 0; s < 4; s++) {
                bf16x8 o;
                #pragma unroll
                for (int k = 0; k < 8; k++) o[k] = Cs[(half * 32 + s * 8 + k) * CST + c];
                *(bf16x8*)(ktp + s * 8) = o;
            }
        }
    } else {
        // Vt transpose
        const int c = tid & 127, half = tid >> 7;
        const int head = (blockIdx.y & 3) * 2 + (c >> 6);
        const int e = c & 63;
        short* vtp = Vt + (((size_t)(b * NH + head)) * HD + e) * T_SEQ + t0 + half * 32;
        #pragma unroll
        for (int s = 0; s < 4; s++) {
            bf16x8 o;
            #pragma unroll
            for (int k = 0; k < 8; k++) o[k] = Cs[(half * 32 + s * 8 + k) * CST + c];
            *(bf16x8*)(vtp + s * 8) = o;
        }
    }
}

// ---------------------------------------------------------------------------
// Kernel 2: per-chunk sums via MFMA: S[e][d] = sum_t Vt[e][t]*Kt[d][t]; ksum[d].
// grid 512, block 256
// ---------------------------------------------------------------------------
__global__ __launch_bounds__(256) void chunk_sum_kernel(
    const short* __restrict__ Ktb, const short* __restrict__ Vt,
    float* __restrict__ Schunk, float* __restrict__ kchunk)
{
    __shared__ short VtL[64 * LDST];
    __shared__ short KtL[64 * LDST];
    __shared__ float ksp[4][64];
    const int bh = blockIdx.x >> 5, c = blockIdx.x & 31;
    const int tid = threadIdx.x;
    const int lane = tid & 63, w = tid >> 6;
    const int fr = lane & 15, fg = lane >> 4;
    #pragma unroll
    for (int it = 0; it < 2; it++) {
        const int qi = it * 256 + tid;           // 0..511
        const int r = qi >> 3, c8 = (qi & 7) * 8;
        *(bf16x8*)&VtL[r * LDST + c8] =
            *(const bf16x8*)(Vt + ((size_t)(bh * HD) + r) * T_SEQ + c * CHUNK + c8);
        *(bf16x8*)&KtL[r * LDST + c8] =
            *(const bf16x8*)(Ktb + ((size_t)(bh * HD) + r) * T_SEQ + c * CHUNK + c8);
    }
    __syncthreads();
    f32x4 acc[4] = {};
    #pragma unroll
    for (int ks = 0; ks < 2; ks++) {
        const bf16x8 av = *(const bf16x8*)&VtL[(w * 16 + fr) * LDST + ks * 32 + fg * 8];
        #pragma unroll
        for (int j = 0; j < 4; j++) {
            const bf16x8 bk = *(const bf16x8*)&KtL[(j * 16 + fr) * LDST + ks * 32 + fg * 8];
            acc[j] = __builtin_amdgcn_mfma_f32_16x16x32_bf16(av, bk, acc[j], 0, 0, 0);
        }
    }
    float* Sout = Schunk + ((size_t)bh * NCHUNK + c) * 4096;   // [e][d]
    #pragma unroll
    for (int j = 0; j < 4; j++)
        #pragma unroll
        for (int reg = 0; reg < 4; reg++)
            Sout[(w * 16 + fg * 4 + reg) * 64 + j * 16 + fr] = acc[j][reg];
    float ps = 0.f;
    #pragma unroll
    for (int t = 0; t < 16; t++) ps += bf2f(KtL[lane * LDST + w * 16 + t]);
    ksp[w][lane] = ps;
    __syncthreads();
    if (tid < 64)
        kchunk[((size_t)bh * NCHUNK + c) * 64 + tid] =
            ksp[0][tid] + ksp[1][tid] + ksp[2][tid] + ksp[3][tid];
}

// ---------------------------------------------------------------------------
// Kernel 3: exclusive prefix over 32 chunks; one scan per thread. grid 260
// ---------------------------------------------------------------------------
__global__ __launch_bounds__(256) void scan_kernel(float* __restrict__ Schunk,
                                                   float* __restrict__ kchunk)
{
    const int gid = blockIdx.x * 256 + threadIdx.x;
    if (blockIdx.x < 256) {
        const int bh = gid >> 12, i = gid & 4095;
        float run = 0.f;
        float* p = Schunk + (size_t)bh * NCHUNK * 4096 + i;
        for (int c = 0; c < NCHUNK; c++) { const float tv = p[c * 4096]; p[c * 4096] = run; run += tv; }
    } else {
        const int idx = gid - 65536;
        const int bh = idx >> 6, d = idx & 63;
        float run = 0.f;
        float* p = kchunk + (size_t)bh * NCHUNK * 64 + d;
        for (int c = 0; c < NCHUNK; c++) { const float tv = p[c * 64]; p[c * 64] = run; run += tv; }
    }
}

// ---------------------------------------------------------------------------
// Kernel 4: intra-chunk via MFMA.
// qn = Qs/(Ksum+eps); A = tril(qn.K^T); attn = qn.Sp^T + A.V^T  (bf16 out)
// grid 512, block 256
// ---------------------------------------------------------------------------
__global__ __launch_bounds__(256) void intra_kernel(
    const short* __restrict__ Qs, const short* __restrict__ Kbf,
    const short* __restrict__ Vt, const float* __restrict__ Schunk,
    const float* __restrict__ kchunk, short* __restrict__ attnb)
{
    __shared__ short B1[64 * LDST];
    __shared__ short B2[64 * LDST];
    __shared__ short KL[64 * LDST];
    __shared__ short VtL[64 * LDST];
    __shared__ short QnL[64 * LDST];
    __shared__ float gsum[4][64];
    __shared__ float kpre[64];
    const int bh = blockIdx.x >> 5, c = blockIdx.x & 31;
    const int tid = threadIdx.x;
    const int lane = tid & 63, w = tid >> 6;
    const int fr = lane & 15, fg = lane >> 4;
    const size_t tdbase = ((size_t)bh * T_SEQ + c * CHUNK) * HD;
    #pragma unroll
    for (int it = 0; it < 2; it++) {
        const int qi = it * 256 + tid;
        const int r = qi >> 3, c8 = (qi & 7) * 8;
        *(bf16x8*)&B1[r * LDST + c8]  = *(const bf16x8*)(Qs + tdbase + r * HD + c8);
        *(bf16x8*)&KL[r * LDST + c8]  = *(const bf16x8*)(Kbf + tdbase + r * HD + c8);
        *(bf16x8*)&VtL[r * LDST + c8] =
            *(const bf16x8*)(Vt + ((size_t)(bh * HD) + r) * T_SEQ + c * CHUNK + c8);
    }
    {
        const float* Sp = Schunk + ((size_t)bh * NCHUNK + c) * 4096;
        #pragma unroll
        for (int it = 0; it < 4; it++) {
            const int qi = it * 256 + tid;
            const int r = qi >> 4, c4 = (qi & 15) * 4;
            const float4 v = *(const float4*)(Sp + r * 64 + c4);
            *(s16x4*)&B2[r * LDST + c4] = (s16x4){f2bf(v.x), f2bf(v.y), f2bf(v.z), f2bf(v.w)};
        }
    }
    if (tid < 64) kpre[tid] = kchunk[((size_t)bh * NCHUNK + c) * 64 + tid];
    __syncthreads();
    {
        float s = 0.f;
        #pragma unroll
        for (int t = 0; t < 16; t++) s += bf2f(KL[(w * 16 + t) * LDST + lane]);
        gsum[w][lane] = s;
    }
    __syncthreads();
    {
        float run = kpre[lane];
        for (int gg = 0; gg < w; gg++) run += gsum[gg][lane];
        #pragma unroll
        for (int t0 = 0; t0 < 16; t0++) {
            const int t = w * 16 + t0;
            run += bf2f(KL[t * LDST + lane]);
            const float qv = bf2f(B1[t * LDST + lane]);
            QnL[t * LDST + lane] = f2bf(qv / (run + EPSV));
        }
    }
    __syncthreads();
    {
        f32x4 a1[4] = {};
        #pragma unroll
        for (int ks = 0; ks < 2; ks++) {
            const bf16x8 aq = *(const bf16x8*)&QnL[(w * 16 + fr) * LDST + ks * 32 + fg * 8];
            #pragma unroll
            for (int j = 0; j < 4; j++) {
                const bf16x8 bk = *(const bf16x8*)&KL[(j * 16 + fr) * LDST + ks * 32 + fg * 8];
                a1[j] = __builtin_amdgcn_mfma_f32_16x16x32_bf16(aq, bk, a1[j], 0, 0, 0);
            }
        }
        const int trow = w * 16 + fg * 4;
        #pragma unroll
        for (int j = 0; j < 4; j++)
            #pragma unroll
            for (int reg = 0; reg < 4; reg++) {
                const int t = trow + reg, s = j * 16 + fr;
                B1[t * LDST + s] = (s <= t) ? f2bf(a1[j][reg]) : (short)0;
            }
    }
    __syncthreads();
    {
        f32x4 a2[4] = {};
        #pragma unroll
        for (int ks = 0; ks < 2; ks++) {
            const bf16x8 aq = *(const bf16x8*)&QnL[(w * 16 + fr) * LDST + ks * 32 + fg * 8];
            const bf16x8 aa = *(const bf16x8*)&B1[(w * 16 + fr) * LDST + ks * 32 + fg * 8];
            #pragma unroll
            for (int j = 0; j < 4; j++) {
                const bf16x8 bs = *(const bf16x8*)&B2[(j * 16 + fr) * LDST + ks * 32 + fg * 8];
                const bf16x8 bv = *(const bf16x8*)&VtL[(j * 16 + fr) * LDST + ks * 32 + fg * 8];
                a2[j] = __builtin_amdgcn_mfma_f32_16x16x32_bf16(aq, bs, a2[j], 0, 0, 0);
                a2[j] = __builtin_amdgcn_mfma_f32_16x16x32_bf16(aa, bv, a2[j], 0, 0, 0);
            }
        }
        short* ap = attnb + tdbase;
        const int trow = w * 16 + fg * 4;
        #pragma unroll
        for (int j = 0; j < 4; j++)
            #pragma unroll
            for (int reg = 0; reg < 4; reg++)
                ap[(trow + reg) * HD + j * 16 + fr] = f2bf(a2[j][reg]);
    }
}

// ---------------------------------------------------------------------------
// Kernel 5: out = attn(permuted) @ Wo^T + bo, 64x64 tile. grid (64,8), 256
// ---------------------------------------------------------------------------
__global__ __launch_bounds__(256) void outproj_mfma_kernel(
    const short* __restrict__ attnb, const short* __restrict__ Wob,
    const float* __restrict__ bo, float* __restrict__ out)
{
    __shared__ short As[64 * 64];
    __shared__ short Bs[64 * 64];
    const int m0 = blockIdx.x * 64;
    const int n0 = blockIdx.y * 64;
    const int tid = threadIdx.x;
    const int lane = tid & 63, w = tid >> 6;
    const int fr = lane & 15, fg = lane >> 4;
    const int lr = lane >> 3, lc = (lane & 7) * 8;
    const int b = m0 >> 11, tbase = m0 & (T_SEQ - 1);
    f32x4 acc[4] = {};
    for (int k0 = 0; k0 < DIMM; k0 += 64) {
        const int h = k0 >> 6;
        #pragma unroll
        for (int it = 0; it < 2; it++) {
            const int r0 = w * 16 + it * 8;
            gload_lds16(attnb + (((size_t)(b * NH + h)) * T_SEQ + tbase + r0 + lr) * HD + lc,
                        &As[r0 * 64]);
            gload_lds16(Wob + (size_t)(n0 + r0 + lr) * DIMM + k0 + lc, &Bs[r0 * 64]);
        }
        __syncthreads();
        #pragma unroll
        for (int ks = 0; ks < 2; ks++) {
            const bf16x8 af = *(const bf16x8*)&As[(w * 16 + fr) * 64 + ks * 32 + fg * 8];
            #pragma unroll
            for (int j = 0; j < 4; j++) {
                const bf16x8 bfr = *(const bf16x8*)&Bs[(j * 16 + fr) * 64 + ks * 32 + fg * 8];
                acc[j] = __builtin_amdgcn_mfma_f32_16x16x32_bf16(af, bfr, acc[j], 0, 0, 0);
            }
        }
        __syncthreads();
    }
    #pragma unroll
    for (int j = 0; j < 4; j++)
        #pragma unroll
        for (int reg = 0; reg < 4; reg++) {
            const int m = m0 + w * 16 + fg * 4 + reg;
            const int n = n0 + j * 16 + fr;
            out[(size_t)m * DIMM + n] = acc[j][reg] + bo[n];
        }
}

// ---------------------------------------------------------------------------
extern "C" void kernel_launch(void* const* d_in, const int* in_sizes, int n_in,
                              void* d_out, int out_size, void* d_ws, size_t ws_size,
                              hipStream_t stream)
{
    const float* x  = (const float*)d_in[0];
    const float* Wq = (const float*)d_in[1];
    const float* Wk = (const float*)d_in[2];
    const float* Wv = (const float*)d_in[3];
    const float* Wo = (const float*)d_in[4];
    const float* bo = (const float*)d_in[5];
    float* out = (float*)d_out;

    const size_t NELEM = (size_t)BB * T_SEQ * DIMM;   // 2,097,152
    short* xb    = (short*)d_ws;                      // [4096][512]
    short* Wcat  = xb + NELEM;                        // [1536][512]
    short* Wob   = Wcat + 786432;                     // [512][512]
    short* Qs    = Wob + 262144;
    short* Kbf   = Qs + NELEM;
    short* Ktb   = Kbf + NELEM;
    short* Vt    = Ktb + NELEM;
    short* attnb = Vt + NELEM;
    float* Schunk = (float*)(attnb + NELEM);                    // [bh][c][e][d]
    float* kchunk = Schunk + (size_t)BB * NH * NCHUNK * 4096;   // [bh][c][d]

    convert_kernel<<<dim3(1536), 256, 0, stream>>>(x, Wq, Wk, Wv, Wo, xb, Wcat, Wob);
    proj_mfma_kernel<<<dim3(64, 12), 256, 0, stream>>>(xb, Wcat, Qs, Kbf, Ktb, Vt);
    chunk_sum_kernel<<<dim3(BB * NH * NCHUNK), 256, 0, stream>>>(Ktb, Vt, Schunk, kchunk);
    scan_kernel<<<dim3(260), 256, 0, stream>>>(Schunk, kchunk);
    intra_kernel<<<dim3(BB * NH * NCHUNK), 256, 0, stream>>>(Qs, Kbf, Vt, Schunk, kchunk, attnb);
    outproj_mfma_kernel<<<dim3(64, 8), 256, 0, stream>>>(attnb, Wob, bo, out);
}